// Round 10
// baseline (316.845 us; speedup 1.0000x reference)
//
#include <hip/hip_runtime.h>
#include <math.h>
#include <utility>

#define BATCH 16384
#define INPUT_DIM 512
#define HIDDEN 1024
#define NROT 32
#define NANG 496   // 32*31/2

typedef _Float16 half8 __attribute__((ext_vector_type(8)));
typedef float    f32x4 __attribute__((ext_vector_type(4)));

// ---------------------------------------------------------------------------
// Split-precision f16 MFMA GEMM (NT): C = epi(A[M,K] @ B[N,K]^T + bias)
// (unchanged — known-good since round 2)
// ---------------------------------------------------------------------------
template<int EPI>
__global__ __launch_bounds__(256) void gemm_nt_mfma(
    const float* __restrict__ A, const float* __restrict__ B,
    const float* __restrict__ bias, float* __restrict__ C,
    int M, int N, int K, int Nout)
{
    constexpr int BK = 32;                    // K per stage (f32 elems)
    __shared__ _Float16 sAh[2][128 * BK];
    __shared__ _Float16 sAl[2][128 * BK];
    __shared__ _Float16 sB [2][128 * BK];     // total 48 KB

    const int tid = threadIdx.x;
    const int m0 = blockIdx.y * 128;
    const int n0 = blockIdx.x * 128;

    const int rA  = tid >> 2;                       // 0..63
    const int k8  = tid & 3;
    const int swW = ((k8 ^ (rA & 3)) << 3);         // swizzled f16 offset in row

    float4 rg[4][2];

    auto load_tile = [&](int kt) {
        const size_t koff = (size_t)kt * BK + k8 * 8;
        const float4* p;
        p = (const float4*)(A + (size_t)(m0 + rA) * K + koff);
        rg[0][0] = p[0]; rg[0][1] = p[1];
        p = (const float4*)(A + (size_t)(m0 + rA + 64) * K + koff);
        rg[1][0] = p[0]; rg[1][1] = p[1];
        const float4 z = make_float4(0.f, 0.f, 0.f, 0.f);
        if (EPI == 0 || (n0 + rA) < N) {
            p = (const float4*)(B + (size_t)(n0 + rA) * K + koff);
            rg[2][0] = p[0]; rg[2][1] = p[1];
        } else { rg[2][0] = z; rg[2][1] = z; }
        if (EPI == 0 || (n0 + rA + 64) < N) {
            p = (const float4*)(B + (size_t)(n0 + rA + 64) * K + koff);
            rg[3][0] = p[0]; rg[3][1] = p[1];
        } else { rg[3][0] = z; rg[3][1] = z; }
    };

    auto cvt_write = [&](int buf) {
        #pragma unroll
        for (int h = 0; h < 2; ++h) {
            const int base = (rA + h * 64) * BK + swW;
            half8 hi, lo;
            const float* f = (const float*)&rg[h][0];
            #pragma unroll
            for (int j = 0; j < 8; ++j) {
                _Float16 hv = (_Float16)f[j];
                hi[j] = hv;
                lo[j] = (_Float16)(f[j] - (float)hv);
            }
            *(half8*)&sAh[buf][base] = hi;
            *(half8*)&sAl[buf][base] = lo;
        }
        #pragma unroll
        for (int h = 0; h < 2; ++h) {
            const int base = (rA + h * 64) * BK + swW;
            half8 bv;
            const float* f = (const float*)&rg[2 + h][0];
            #pragma unroll
            for (int j = 0; j < 8; ++j) bv[j] = (_Float16)f[j];
            *(half8*)&sB[buf][base] = bv;
        }
    };

    const int lane = tid & 63;
    const int wid  = tid >> 6;
    const int wr = wid >> 1, wc = wid & 1;
    const int fr = lane & 15, fq = lane >> 4;
    const int swR   = ((fq ^ (fr & 3)) << 3);
    const int aBase = (wr * 64 + fr) * BK + swR;
    const int bBase = (wc * 64 + fr) * BK + swR;

    f32x4 acc[4][4];
    #pragma unroll
    for (int i = 0; i < 4; ++i)
        #pragma unroll
        for (int j = 0; j < 4; ++j) acc[i][j] = (f32x4)(0.f);

    const int NT = K / BK;
    load_tile(0);
    cvt_write(0);
    int cur = 0;

    for (int kt = 0; kt < NT; ++kt) {
        const bool more = (kt + 1 < NT);
        if (more) load_tile(kt + 1);
        __syncthreads();

        half8 ah[4], al[4], bb[4];
        #pragma unroll
        for (int f = 0; f < 4; ++f) {
            ah[f] = *(const half8*)&sAh[cur][aBase + f * 16 * BK];
            al[f] = *(const half8*)&sAl[cur][aBase + f * 16 * BK];
            bb[f] = *(const half8*)&sB [cur][bBase + f * 16 * BK];
        }
        #pragma unroll
        for (int fm = 0; fm < 4; ++fm)
            #pragma unroll
            for (int fn = 0; fn < 4; ++fn) {
                acc[fm][fn] = __builtin_amdgcn_mfma_f32_16x16x32_f16(
                    al[fm], bb[fn], acc[fm][fn], 0, 0, 0);
                acc[fm][fn] = __builtin_amdgcn_mfma_f32_16x16x32_f16(
                    ah[fm], bb[fn], acc[fm][fn], 0, 0, 0);
            }

        if (more) cvt_write(cur ^ 1);
        cur ^= 1;
    }

    if (EPI == 0) {
        #pragma unroll
        for (int fn = 0; fn < 4; ++fn) {
            const int col = n0 + wc * 64 + fn * 16 + fr;
            const float bv = bias[col];
            #pragma unroll
            for (int fm = 0; fm < 4; ++fm) {
                const int row0 = m0 + wr * 64 + fm * 16 + fq * 4;
                #pragma unroll
                for (int r = 0; r < 4; ++r)
                    C[(size_t)(row0 + r) * Nout + col] =
                        fmaxf(acc[fm][fn][r] + bv, 0.f);
            }
        }
    } else {
        #pragma unroll
        for (int fn = 0; fn < 4; ++fn) {
            const int col = n0 + wc * 64 + fn * 16 + fr;
            if (col < Nout) {
                const float bv = bias[col];
                #pragma unroll
                for (int fm = 0; fm < 4; ++fm) {
                    const int row0 = m0 + wr * 64 + fm * 16 + fq * 4;
                    #pragma unroll
                    for (int r = 0; r < 4; ++r) {
                        const float ang = acc[fm][fn][r] + bv;
                        float s, c;
                        __sincosf(ang, &s, &c);
                        *(float2*)(C + ((size_t)(row0 + r) * Nout + col) * 2) =
                            make_float2(c, s);
                    }
                }
            }
        }
    }
}

// ---------------------------------------------------------------------------
// Givens rotation chain — scalar rows, occupancy-first:
//   - Round-9 diagnosis: all pipes idle; BPB=8 gave only 2048 blocks = 8
//     blocks/CU = 16 waves/CU GRID CAP (occ 39%). Fix: 4 batches per
//     128-thread block -> 4096 blocks = 16 blocks/CU = 2048 thr/CU = 32
//     waves/CU, with launch_bounds(128,8) (<=64 VGPR) and 8KB LDS so
//     neither VGPR nor LDS caps below the grid.
//   - Thread = (batch, row): v[32] in regs (~50 VGPR). Chain staged in 2
//     halves of 124 float4/batch (7.94KB); groups of 2 ds_read_b128
//     (4 rotations) then 16 VALU ops, template-unrolled (compile-time
//     offsets + IJ indices). Broadcast reads (32 lanes same addr) are
//     conflict-free; 2 batches/wave -> addresses 16 banks apart.
//   - Output transpose in 2 phases reusing the same 8KB buffer.
// ---------------------------------------------------------------------------
struct IJTbl { unsigned char i[NANG]; unsigned char j[NANG]; };
constexpr IJTbl make_ij_tbl() {
    IJTbl t{};
    int k = 0;
    for (int i = 0; i < NROT - 1; ++i)
        for (int j = i + 1; j < NROT; ++j) { t.i[k] = (unsigned char)i; t.j[k] = (unsigned char)j; ++k; }
    return t;
}
constexpr IJTbl IJT = make_ij_tbl();

template<int M>   // M = f4 index 0..247: rotations 2M, 2M+1
__device__ __forceinline__ void rot_pair(const f32x4 q, float (&v)[NROT]) {
    {
        constexpr int k = 2 * M;
        constexpr int i = IJT.i[k], j = IJT.j[k];
        const float vi = v[i], vj = v[j];
        v[i] = fmaf(q[0], vi,  q[1] * vj);
        v[j] = fmaf(q[0], vj, -q[1] * vi);
    }
    {
        constexpr int k = 2 * M + 1;
        constexpr int i = IJT.i[k], j = IJT.j[k];
        const float vi = v[i], vj = v[j];
        v[i] = fmaf(q[2], vi,  q[3] * vj);
        v[j] = fmaf(q[2], vj, -q[3] * vi);
    }
}

template<int G, int H>   // group: 2 f4 reads = 4 rotations
__device__ __forceinline__ void group2(const float* __restrict__ lcs,
                                       float (&v)[NROT]) {
    const f32x4 s0 = *(const f32x4*)(lcs + (G * 2 + 0) * 4);
    const f32x4 s1 = *(const f32x4*)(lcs + (G * 2 + 1) * 4);
    rot_pair<H * 124 + G * 2 + 0>(s0, v);
    rot_pair<H * 124 + G * 2 + 1>(s1, v);
}

template<int H, size_t... Gs>
__device__ __forceinline__ void run_half(const float* __restrict__ lcs,
                                         float (&v)[NROT],
                                         std::index_sequence<Gs...>) {
    (group2<(int)Gs, H>(lcs, v), ...);
}

__global__ __launch_bounds__(128, 8) void rotate_kernel(
    const float4* __restrict__ cs4, float* __restrict__ out)
{
    __shared__ float lds[2048];            // 8 KB (staging + transpose reuse)

    const int tid = threadIdx.x;
    const int bl  = tid >> 5;              // batch within block (0..3)
    const int r   = tid & 31;              // row of R
    const size_t bbase = (size_t)blockIdx.x * 4;

    float v[NROT];
    #pragma unroll
    for (int c = 0; c < NROT; ++c) v[c] = (c == r) ? 1.f : 0.f;

    float4* l4 = (float4*)lds;             // [4][124] float4 per half
    const float* lcs = lds + bl * 124 * 4;

    #pragma unroll
    for (int h = 0; h < 2; ++h) {
        if (h) __syncthreads();            // previous half's reads complete
        #pragma unroll
        for (int it = 0; it < 4; ++it) {
            const int idx = it * 128 + tid;
            if (idx < 496) {
                const int b = idx / 124, m = idx - b * 124;
                l4[b * 124 + m] = cs4[(bbase + b) * 248 + h * 124 + m];
            }
        }
        __syncthreads();
        if (h == 0) run_half<0>(lcs, v, std::make_index_sequence<62>{});
        else        run_half<1>(lcs, v, std::make_index_sequence<62>{});
    }
    __syncthreads();                       // chain reads done; reuse lds

    // ---- output: 2 phases (2 batches each), swizzled LDS transpose ----
    #pragma unroll
    for (int ph = 0; ph < 2; ++ph) {
        if (ph) __syncthreads();
        if ((bl >> 1) == ph) {
            #pragma unroll
            for (int q = 0; q < 8; ++q) {
                *(float4*)&lds[(bl & 1) * 1024 + r * 32 + ((q ^ (r & 7)) << 2)] =
                    make_float4(v[q*4], v[q*4+1], v[q*4+2], v[q*4+3]);
            }
        }
        __syncthreads();
        #pragma unroll
        for (int s = 0; s < 4; ++s) {
            const int f4i = s * 128 + tid;          // 0..511
            const int lb  = f4i >> 8;               // 0..1
            const int row = (f4i >> 3) & 31;
            const int qq  = f4i & 7;
            const float4 val =
                *(const float4*)&lds[lb * 1024 + row * 32 + ((qq ^ (row & 7)) << 2)];
            *(float4*)(out + (bbase + ph * 2 + lb) * 1024 + row * 32 + qq * 4) = val;
        }
    }
}

// ---------------------------------------------------------------------------
extern "C" void kernel_launch(void* const* d_in, const int* in_sizes, int n_in,
                              void* d_out, int out_size, void* d_ws, size_t ws_size,
                              hipStream_t stream)
{
    const float* x  = (const float*)d_in[0];   // [16384, 512]
    const float* W1 = (const float*)d_in[1];   // [1024, 512]
    const float* b1 = (const float*)d_in[2];   // [1024]
    const float* W2 = (const float*)d_in[3];   // [496, 1024]
    const float* b2 = (const float*)d_in[4];   // [496]
    float* out = (float*)d_out;                // [16384, 32, 32]

    float* h  = out;              // d_out (64 MB) doubles as h scratch
    float* cs = (float*)d_ws;     // [16384][496] float2 = 65 MB

    gemm_nt_mfma<0><<<dim3(HIDDEN / 128, BATCH / 128), 256, 0, stream>>>(
        x, W1, b1, h, BATCH, HIDDEN, INPUT_DIM, HIDDEN);

    gemm_nt_mfma<1><<<dim3((NANG + 127) / 128, BATCH / 128), 256, 0, stream>>>(
        h, W2, b2, cs, BATCH, NANG, HIDDEN, NANG);

    rotate_kernel<<<dim3(BATCH / 4), 128, 0, stream>>>(
        (const float4*)cs, out);
}

// Round 11
// 178.131 us; speedup vs baseline: 1.7787x; 1.7787x over previous
//
#include <hip/hip_runtime.h>
#include <math.h>
#include <utility>

#define BATCH 16384
#define INPUT_DIM 512
#define HIDDEN 1024
#define NROT 32
#define NANG 496   // 32*31/2

typedef _Float16 half8 __attribute__((ext_vector_type(8)));
typedef float    f32x4 __attribute__((ext_vector_type(4)));

// ---------------------------------------------------------------------------
// f16 MFMA GEMM (NT): C = epi(A[M,K] @ B[N,K]^T + bias)
// SPLIT=true: A = Ah + Al residual split (2 MFMA passes, ~f32 accuracy).
// SPLIT=false: single-pass f16 (half the MFMA/cvt work; adds ~5e-4 angle err,
//              well under the 0.02 threshold — used for GEMM2 only).
//   EPI=0: relu(acc+bias) -> float C[M][Nout]
//   EPI=1: sincos(acc+bias) -> float2 C[M][Nout], col guarded (< Nout)
// ---------------------------------------------------------------------------
template<int EPI, bool SPLIT>
__global__ __launch_bounds__(256) void gemm_nt_mfma(
    const float* __restrict__ A, const float* __restrict__ B,
    const float* __restrict__ bias, float* __restrict__ C,
    int M, int N, int K, int Nout)
{
    constexpr int BK = 32;                    // K per stage (f32 elems)
    __shared__ _Float16 sAh[2][128 * BK];
    __shared__ _Float16 sAl[2][SPLIT ? 128 * BK : 8];
    __shared__ _Float16 sB [2][128 * BK];     // 48 KB split / 32 KB single

    const int tid = threadIdx.x;
    const int m0 = blockIdx.y * 128;
    const int n0 = blockIdx.x * 128;

    const int rA  = tid >> 2;                       // 0..63
    const int k8  = tid & 3;
    const int swW = ((k8 ^ (rA & 3)) << 3);         // swizzled f16 offset in row

    float4 rg[4][2];

    auto load_tile = [&](int kt) {
        const size_t koff = (size_t)kt * BK + k8 * 8;
        const float4* p;
        p = (const float4*)(A + (size_t)(m0 + rA) * K + koff);
        rg[0][0] = p[0]; rg[0][1] = p[1];
        p = (const float4*)(A + (size_t)(m0 + rA + 64) * K + koff);
        rg[1][0] = p[0]; rg[1][1] = p[1];
        const float4 z = make_float4(0.f, 0.f, 0.f, 0.f);
        if (EPI == 0 || (n0 + rA) < N) {
            p = (const float4*)(B + (size_t)(n0 + rA) * K + koff);
            rg[2][0] = p[0]; rg[2][1] = p[1];
        } else { rg[2][0] = z; rg[2][1] = z; }
        if (EPI == 0 || (n0 + rA + 64) < N) {
            p = (const float4*)(B + (size_t)(n0 + rA + 64) * K + koff);
            rg[3][0] = p[0]; rg[3][1] = p[1];
        } else { rg[3][0] = z; rg[3][1] = z; }
    };

    auto cvt_write = [&](int buf) {
        #pragma unroll
        for (int h = 0; h < 2; ++h) {
            const int base = (rA + h * 64) * BK + swW;
            half8 hi, lo;
            const float* f = (const float*)&rg[h][0];
            #pragma unroll
            for (int j = 0; j < 8; ++j) {
                _Float16 hv = (_Float16)f[j];
                hi[j] = hv;
                if constexpr (SPLIT) lo[j] = (_Float16)(f[j] - (float)hv);
            }
            *(half8*)&sAh[buf][base] = hi;
            if constexpr (SPLIT) *(half8*)&sAl[buf][base] = lo;
        }
        #pragma unroll
        for (int h = 0; h < 2; ++h) {
            const int base = (rA + h * 64) * BK + swW;
            half8 bv;
            const float* f = (const float*)&rg[2 + h][0];
            #pragma unroll
            for (int j = 0; j < 8; ++j) bv[j] = (_Float16)f[j];
            *(half8*)&sB[buf][base] = bv;
        }
    };

    const int lane = tid & 63;
    const int wid  = tid >> 6;
    const int wr = wid >> 1, wc = wid & 1;
    const int fr = lane & 15, fq = lane >> 4;
    const int swR   = ((fq ^ (fr & 3)) << 3);
    const int aBase = (wr * 64 + fr) * BK + swR;
    const int bBase = (wc * 64 + fr) * BK + swR;

    f32x4 acc[4][4];
    #pragma unroll
    for (int i = 0; i < 4; ++i)
        #pragma unroll
        for (int j = 0; j < 4; ++j) acc[i][j] = (f32x4)(0.f);

    const int NT = K / BK;
    load_tile(0);
    cvt_write(0);
    int cur = 0;

    for (int kt = 0; kt < NT; ++kt) {
        const bool more = (kt + 1 < NT);
        if (more) load_tile(kt + 1);
        __syncthreads();

        half8 ah[4], al[4], bb[4];
        #pragma unroll
        for (int f = 0; f < 4; ++f) {
            ah[f] = *(const half8*)&sAh[cur][aBase + f * 16 * BK];
            if constexpr (SPLIT)
                al[f] = *(const half8*)&sAl[cur][aBase + f * 16 * BK];
            bb[f] = *(const half8*)&sB [cur][bBase + f * 16 * BK];
        }
        #pragma unroll
        for (int fm = 0; fm < 4; ++fm)
            #pragma unroll
            for (int fn = 0; fn < 4; ++fn) {
                if constexpr (SPLIT)
                    acc[fm][fn] = __builtin_amdgcn_mfma_f32_16x16x32_f16(
                        al[fm], bb[fn], acc[fm][fn], 0, 0, 0);
                acc[fm][fn] = __builtin_amdgcn_mfma_f32_16x16x32_f16(
                    ah[fm], bb[fn], acc[fm][fn], 0, 0, 0);
            }

        if (more) cvt_write(cur ^ 1);
        cur ^= 1;
    }

    if (EPI == 0) {
        #pragma unroll
        for (int fn = 0; fn < 4; ++fn) {
            const int col = n0 + wc * 64 + fn * 16 + fr;
            const float bv = bias[col];
            #pragma unroll
            for (int fm = 0; fm < 4; ++fm) {
                const int row0 = m0 + wr * 64 + fm * 16 + fq * 4;
                #pragma unroll
                for (int r = 0; r < 4; ++r)
                    C[(size_t)(row0 + r) * Nout + col] =
                        fmaxf(acc[fm][fn][r] + bv, 0.f);
            }
        }
    } else {
        #pragma unroll
        for (int fn = 0; fn < 4; ++fn) {
            const int col = n0 + wc * 64 + fn * 16 + fr;
            if (col < Nout) {
                const float bv = bias[col];
                #pragma unroll
                for (int fm = 0; fm < 4; ++fm) {
                    const int row0 = m0 + wr * 64 + fm * 16 + fq * 4;
                    #pragma unroll
                    for (int r = 0; r < 4; ++r) {
                        const float ang = acc[fm][fn][r] + bv;
                        float s, c;
                        __sincosf(ang, &s, &c);
                        *(float2*)(C + ((size_t)(row0 + r) * Nout + col) * 2) =
                            make_float2(c, s);
                    }
                }
            }
        }
    }
}

// ---------------------------------------------------------------------------
// Givens rotation chain — global-JIT loads, occupancy-first (R4 fixed):
//   - R4 (84us) had VGPR=56 (8 waves/SIMD eligible) but its 32KB LDS
//     transpose buffer capped residency at 5 blocks/CU (occ 40%). Here:
//     8KB LDS (4-phase output transpose) -> cap 20 blocks; grid 2048 x
//     256thr = exactly 8 blocks/CU x 4 waves = 32 waves/CU, one generation.
//   - Chain: thread=(batch,row), v[32] in regs; 124 groups of {2x float4
//     uniform global load (compile-time offsets), 4 rotations}. Loads are
//     JIT-scheduled by the compiler (proven-correct R3/R4); at 8 waves/SIMD
//     the per-group compute (8 waves x 32cyc = 256cyc) covers L2 latency.
//   - No launch_bounds min-waves (R10 spill trap), no inline asm (R7 trap),
//     no barriers in the chain.
// ---------------------------------------------------------------------------
struct IJTbl { unsigned char i[NANG]; unsigned char j[NANG]; };
constexpr IJTbl make_ij_tbl() {
    IJTbl t{};
    int k = 0;
    for (int i = 0; i < NROT - 1; ++i)
        for (int j = i + 1; j < NROT; ++j) { t.i[k] = (unsigned char)i; t.j[k] = (unsigned char)j; ++k; }
    return t;
}
constexpr IJTbl IJT = make_ij_tbl();

template<int M>   // M = f4 index 0..247: rotations 2M, 2M+1
__device__ __forceinline__ void rot_pair(const f32x4 q, float (&v)[NROT]) {
    {
        constexpr int k = 2 * M;
        constexpr int i = IJT.i[k], j = IJT.j[k];
        const float vi = v[i], vj = v[j];
        v[i] = fmaf(q[0], vi,  q[1] * vj);
        v[j] = fmaf(q[0], vj, -q[1] * vi);
    }
    {
        constexpr int k = 2 * M + 1;
        constexpr int i = IJT.i[k], j = IJT.j[k];
        const float vi = v[i], vj = v[j];
        v[i] = fmaf(q[2], vi,  q[3] * vj);
        v[j] = fmaf(q[2], vj, -q[3] * vi);
    }
}

template<int G>   // group: 2 contiguous f4 loads = 4 rotations
__device__ __forceinline__ void jit_group(const f32x4* __restrict__ p,
                                          float (&v)[NROT]) {
    const f32x4 q0 = p[2 * G + 0];
    const f32x4 q1 = p[2 * G + 1];
    rot_pair<2 * G + 0>(q0, v);
    rot_pair<2 * G + 1>(q1, v);
}

template<size_t... Gs>
__device__ __forceinline__ void run_chain(const f32x4* __restrict__ p,
                                          float (&v)[NROT],
                                          std::index_sequence<Gs...>) {
    (jit_group<(int)Gs>(p, v), ...);
}

__global__ __launch_bounds__(256) void rotate_kernel(
    const f32x4* __restrict__ cs4, float* __restrict__ out)
{
    __shared__ float lds[2048];            // 8 KB: 4-phase output transpose

    const int tid = threadIdx.x;
    const int bl  = tid >> 5;              // batch within block (0..7)
    const int r   = tid & 31;              // row of R
    const size_t bbase = (size_t)blockIdx.x * 8;

    const f32x4* __restrict__ p = cs4 + (bbase + bl) * 248;

    float v[NROT];
    #pragma unroll
    for (int c = 0; c < NROT; ++c) v[c] = (c == r) ? 1.f : 0.f;

    run_chain(p, v, std::make_index_sequence<124>{});

    // ---- 4-phase coalesced store via swizzled 8KB LDS transpose ----
    #pragma unroll
    for (int ph = 0; ph < 4; ++ph) {
        if (ph) __syncthreads();
        if ((bl >> 1) == ph) {             // this phase's 2 batches write
            #pragma unroll
            for (int q = 0; q < 8; ++q) {
                *(float4*)&lds[(bl & 1) * 1024 + r * 32 + ((q ^ (r & 7)) << 2)] =
                    make_float4(v[q*4], v[q*4+1], v[q*4+2], v[q*4+3]);
            }
        }
        __syncthreads();
        #pragma unroll
        for (int s = 0; s < 2; ++s) {      // 512 f4 = 8KB, 2 per thread
            const int f4i = s * 256 + tid;
            const int lb  = f4i >> 8;              // 0..1
            const int row = (f4i >> 3) & 31;
            const int qq  = f4i & 7;
            const float4 val =
                *(const float4*)&lds[lb * 1024 + row * 32 + ((qq ^ (row & 7)) << 2)];
            *(float4*)(out + (bbase + ph * 2 + lb) * 1024 + row * 32 + qq * 4) = val;
        }
    }
}

// ---------------------------------------------------------------------------
extern "C" void kernel_launch(void* const* d_in, const int* in_sizes, int n_in,
                              void* d_out, int out_size, void* d_ws, size_t ws_size,
                              hipStream_t stream)
{
    const float* x  = (const float*)d_in[0];   // [16384, 512]
    const float* W1 = (const float*)d_in[1];   // [1024, 512]
    const float* b1 = (const float*)d_in[2];   // [1024]
    const float* W2 = (const float*)d_in[3];   // [496, 1024]
    const float* b2 = (const float*)d_in[4];   // [496]
    float* out = (float*)d_out;                // [16384, 32, 32]

    float* h  = out;              // d_out (64 MB) doubles as h scratch
    float* cs = (float*)d_ws;     // [16384][496] float2 = 65 MB

    // h = relu(x @ W1^T + b1)  — split (accuracy feeds everything downstream)
    gemm_nt_mfma<0, true><<<dim3(HIDDEN / 128, BATCH / 128), 256, 0, stream>>>(
        x, W1, b1, h, BATCH, HIDDEN, INPUT_DIM, HIDDEN);

    // cs = (cos,sin)(h @ W2^T + b2) — single-pass f16 (half the MFMA work)
    gemm_nt_mfma<1, false><<<dim3((NANG + 127) / 128, BATCH / 128), 256, 0, stream>>>(
        h, W2, b2, cs, BATCH, NANG, HIDDEN, NANG);

    rotate_kernel<<<dim3(BATCH / 8), 256, 0, stream>>>(
        (const f32x4*)cs, out);
}

// Round 12
// 147.249 us; speedup vs baseline: 2.1518x; 1.2097x over previous
//
#include <hip/hip_runtime.h>
#include <math.h>
#include <utility>

#define BATCH 16384
#define INPUT_DIM 512
#define HIDDEN 1024
#define NROT 32
#define NANG 496   // 32*31/2

typedef _Float16 half8 __attribute__((ext_vector_type(8)));
typedef float    f32x4 __attribute__((ext_vector_type(4)));

// ---------------------------------------------------------------------------
// f16 MFMA GEMM (NT): C = epi(A[M,K] @ B[N,K]^T + bias)   (unchanged, R11)
// ---------------------------------------------------------------------------
template<int EPI, bool SPLIT>
__global__ __launch_bounds__(256) void gemm_nt_mfma(
    const float* __restrict__ A, const float* __restrict__ B,
    const float* __restrict__ bias, float* __restrict__ C,
    int M, int N, int K, int Nout)
{
    constexpr int BK = 32;
    __shared__ _Float16 sAh[2][128 * BK];
    __shared__ _Float16 sAl[2][SPLIT ? 128 * BK : 8];
    __shared__ _Float16 sB [2][128 * BK];

    const int tid = threadIdx.x;
    const int m0 = blockIdx.y * 128;
    const int n0 = blockIdx.x * 128;

    const int rA  = tid >> 2;
    const int k8  = tid & 3;
    const int swW = ((k8 ^ (rA & 3)) << 3);

    float4 rg[4][2];

    auto load_tile = [&](int kt) {
        const size_t koff = (size_t)kt * BK + k8 * 8;
        const float4* p;
        p = (const float4*)(A + (size_t)(m0 + rA) * K + koff);
        rg[0][0] = p[0]; rg[0][1] = p[1];
        p = (const float4*)(A + (size_t)(m0 + rA + 64) * K + koff);
        rg[1][0] = p[0]; rg[1][1] = p[1];
        const float4 z = make_float4(0.f, 0.f, 0.f, 0.f);
        if (EPI == 0 || (n0 + rA) < N) {
            p = (const float4*)(B + (size_t)(n0 + rA) * K + koff);
            rg[2][0] = p[0]; rg[2][1] = p[1];
        } else { rg[2][0] = z; rg[2][1] = z; }
        if (EPI == 0 || (n0 + rA + 64) < N) {
            p = (const float4*)(B + (size_t)(n0 + rA + 64) * K + koff);
            rg[3][0] = p[0]; rg[3][1] = p[1];
        } else { rg[3][0] = z; rg[3][1] = z; }
    };

    auto cvt_write = [&](int buf) {
        #pragma unroll
        for (int h = 0; h < 2; ++h) {
            const int base = (rA + h * 64) * BK + swW;
            half8 hi, lo;
            const float* f = (const float*)&rg[h][0];
            #pragma unroll
            for (int j = 0; j < 8; ++j) {
                _Float16 hv = (_Float16)f[j];
                hi[j] = hv;
                if constexpr (SPLIT) lo[j] = (_Float16)(f[j] - (float)hv);
            }
            *(half8*)&sAh[buf][base] = hi;
            if constexpr (SPLIT) *(half8*)&sAl[buf][base] = lo;
        }
        #pragma unroll
        for (int h = 0; h < 2; ++h) {
            const int base = (rA + h * 64) * BK + swW;
            half8 bv;
            const float* f = (const float*)&rg[2 + h][0];
            #pragma unroll
            for (int j = 0; j < 8; ++j) bv[j] = (_Float16)f[j];
            *(half8*)&sB[buf][base] = bv;
        }
    };

    const int lane = tid & 63;
    const int wid  = tid >> 6;
    const int wr = wid >> 1, wc = wid & 1;
    const int fr = lane & 15, fq = lane >> 4;
    const int swR   = ((fq ^ (fr & 3)) << 3);
    const int aBase = (wr * 64 + fr) * BK + swR;
    const int bBase = (wc * 64 + fr) * BK + swR;

    f32x4 acc[4][4];
    #pragma unroll
    for (int i = 0; i < 4; ++i)
        #pragma unroll
        for (int j = 0; j < 4; ++j) acc[i][j] = (f32x4)(0.f);

    const int NT = K / BK;
    load_tile(0);
    cvt_write(0);
    int cur = 0;

    for (int kt = 0; kt < NT; ++kt) {
        const bool more = (kt + 1 < NT);
        if (more) load_tile(kt + 1);
        __syncthreads();

        half8 ah[4], al[4], bb[4];
        #pragma unroll
        for (int f = 0; f < 4; ++f) {
            ah[f] = *(const half8*)&sAh[cur][aBase + f * 16 * BK];
            if constexpr (SPLIT)
                al[f] = *(const half8*)&sAl[cur][aBase + f * 16 * BK];
            bb[f] = *(const half8*)&sB [cur][bBase + f * 16 * BK];
        }
        #pragma unroll
        for (int fm = 0; fm < 4; ++fm)
            #pragma unroll
            for (int fn = 0; fn < 4; ++fn) {
                if constexpr (SPLIT)
                    acc[fm][fn] = __builtin_amdgcn_mfma_f32_16x16x32_f16(
                        al[fm], bb[fn], acc[fm][fn], 0, 0, 0);
                acc[fm][fn] = __builtin_amdgcn_mfma_f32_16x16x32_f16(
                    ah[fm], bb[fn], acc[fm][fn], 0, 0, 0);
            }

        if (more) cvt_write(cur ^ 1);
        cur ^= 1;
    }

    if (EPI == 0) {
        #pragma unroll
        for (int fn = 0; fn < 4; ++fn) {
            const int col = n0 + wc * 64 + fn * 16 + fr;
            const float bv = bias[col];
            #pragma unroll
            for (int fm = 0; fm < 4; ++fm) {
                const int row0 = m0 + wr * 64 + fm * 16 + fq * 4;
                #pragma unroll
                for (int r = 0; r < 4; ++r)
                    C[(size_t)(row0 + r) * Nout + col] =
                        fmaxf(acc[fm][fn][r] + bv, 0.f);
            }
        }
    } else {
        #pragma unroll
        for (int fn = 0; fn < 4; ++fn) {
            const int col = n0 + wc * 64 + fn * 16 + fr;
            if (col < Nout) {
                const float bv = bias[col];
                #pragma unroll
                for (int fm = 0; fm < 4; ++fm) {
                    const int row0 = m0 + wr * 64 + fm * 16 + fq * 4;
                    #pragma unroll
                    for (int r = 0; r < 4; ++r) {
                        const float ang = acc[fm][fn][r] + bv;
                        float s, c;
                        __sincosf(ang, &s, &c);
                        *(float2*)(C + ((size_t)(row0 + r) * Nout + col) * 2) =
                            make_float2(c, s);
                    }
                }
            }
        }
    }
}

// ---------------------------------------------------------------------------
// Rotate — chunked chain + MFMA combine tree:
//   R = G1..G496 = C0*C1*C2*C3, chunks of 124 rotations. Block = 2 batches,
//   4 waves; wave w computes chunk C_w for both batches (half-wave each) via
//   the proven row-per-thread chain — 4x shorter chain, 4x more threads.
//   Then L1: P0=C0*C1, P1=C2*C3; L2: R=P0*P1 via mfma_f32_16x16x32_f16
//   (f16 operands / f32 accum; left factors row-major, right factors stored
//   transposed -> both operands are NT row-reads, same swizzle as the GEMM).
//   cs staged coalesced into LDS; all chain reads are LDS broadcast with
//   compile-time offsets. 32 KB LDS -> 5 blocks/CU.
// LDS map (bytes): [0,8K) stage(7936B) then L2-out f32; [8K,16K) chunk lefts
// f16 (2 batches x {C0,C2}); [16K,24K) chunk rights transposed ({C1,C3});
// [24K,28K) P0 row-major f16; [28K,32K) P1 transposed f16.
// ---------------------------------------------------------------------------
struct IJTbl { unsigned char i[NANG]; unsigned char j[NANG]; };
constexpr IJTbl make_ij_tbl() {
    IJTbl t{};
    int k = 0;
    for (int i = 0; i < NROT - 1; ++i)
        for (int j = i + 1; j < NROT; ++j) { t.i[k] = (unsigned char)i; t.j[k] = (unsigned char)j; ++k; }
    return t;
}
constexpr IJTbl IJT = make_ij_tbl();

template<int M>   // M = f4 index 0..247: rotations 2M, 2M+1
__device__ __forceinline__ void rot_pair(const f32x4 q, float (&v)[NROT]) {
    {
        constexpr int k = 2 * M;
        constexpr int i = IJT.i[k], j = IJT.j[k];
        const float vi = v[i], vj = v[j];
        v[i] = fmaf(q[0], vi,  q[1] * vj);
        v[j] = fmaf(q[0], vj, -q[1] * vi);
    }
    {
        constexpr int k = 2 * M + 1;
        constexpr int i = IJT.i[k], j = IJT.j[k];
        const float vi = v[i], vj = v[j];
        v[i] = fmaf(q[2], vi,  q[3] * vj);
        v[j] = fmaf(q[2], vj, -q[3] * vi);
    }
}

template<int W, int T>
__device__ __forceinline__ void chain_grp(const float* __restrict__ lcs,
                                          float (&v)[NROT]) {
    const f32x4 q = *(const f32x4*)(lcs + (62 * W + T) * 4);
    rot_pair<62 * W + T>(q, v);
}

template<int W, size_t... Ts>
__device__ __forceinline__ void chain_runW(const float* __restrict__ lcs,
                                           float (&v)[NROT],
                                           std::index_sequence<Ts...>) {
    (chain_grp<W, (int)Ts>(lcs, v), ...);
}

// f16 LDS region bases (f16 index units)
#define LROW_H 4096
#define RT_H   8192
#define PL_H   12288
#define PRT_H  14336

template<int W>
__device__ __forceinline__ void chain_and_store(const float* __restrict__ lcs,
                                                _Float16* __restrict__ lh,
                                                int half, int r) {
    float v[NROT];
    #pragma unroll
    for (int c = 0; c < NROT; ++c) v[c] = (c == r) ? 1.f : 0.f;
    chain_runW<W>(lcs, v, std::make_index_sequence<62>{});

    if constexpr ((W & 1) == 0) {
        // left factor: row-major, GEMM-style k-chunk XOR swizzle
        const int base = LROW_H + (half * 2 + (W >> 1)) * 1024;
        #pragma unroll
        for (int kq = 0; kq < 4; ++kq) {
            half8 hv;
            #pragma unroll
            for (int j = 0; j < 8; ++j) hv[j] = (_Float16)v[kq * 8 + j];
            *(half8*)&lh[base + r * 32 + ((kq ^ (r & 3)) << 3)] = hv;
        }
    } else {
        // right factor: store transposed (Ct[c][r] = v[c]), same swizzle
        const int base = RT_H + (half * 2 + (W >> 1)) * 1024;
        #pragma unroll
        for (int c = 0; c < NROT; ++c)
            lh[base + c * 32 + (((r >> 3) ^ (c & 3)) << 3) + (r & 7)] =
                (_Float16)v[c];
    }
}

__global__ __launch_bounds__(256) void rotate_kernel(
    const float4* __restrict__ cs4, float* __restrict__ out)
{
    __shared__ float smem[8192];   // 32 KB
    _Float16* lh = (_Float16*)smem;

    const int tid  = threadIdx.x;
    const int wid  = tid >> 6;             // wave = chunk index
    const int lane = tid & 63;
    const int half = (tid >> 5) & 1;       // batch within block
    const int r    = tid & 31;             // row
    const int fr = lane & 15, fq = lane >> 4;
    const size_t b0 = (size_t)blockIdx.x * 2;

    // ---- stage both batches' cs coalesced: 496 float4 ----
    float4* l4 = (float4*)smem;
    #pragma unroll
    for (int t = 0; t < 2; ++t) {
        const int idx = t * 256 + tid;
        if (idx < 496) {
            const int ba = idx >= 248;
            const int m  = idx - ba * 248;
            l4[ba * 248 + m] = cs4[(b0 + ba) * 248 + m];
        }
    }
    __syncthreads();

    // ---- chunk chains (wave-uniform branch) ----
    const float* lcs = smem + half * 992;
    if      (wid == 0) chain_and_store<0>(lcs, lh, half, r);
    else if (wid == 1) chain_and_store<1>(lcs, lh, half, r);
    else if (wid == 2) chain_and_store<2>(lcs, lh, half, r);
    else               chain_and_store<3>(lcs, lh, half, r);
    __syncthreads();

    // ---- L1: wave w -> batch (w>>1), product P_(w&1) = C_{2p} * C_{2p+1}
    {
        const int ba = wid >> 1, pi = wid & 1;
        const int Ab = LROW_H + (ba * 2 + pi) * 1024;
        const int Bb = RT_H   + (ba * 2 + pi) * 1024;
        half8 a[2], b[2];
        #pragma unroll
        for (int mi = 0; mi < 2; ++mi) {
            a[mi] = *(const half8*)&lh[Ab + (mi * 16 + fr) * 32 + ((fq ^ (fr & 3)) << 3)];
            b[mi] = *(const half8*)&lh[Bb + (mi * 16 + fr) * 32 + ((fq ^ (fr & 3)) << 3)];
        }
        f32x4 d[2][2];
        #pragma unroll
        for (int mi = 0; mi < 2; ++mi)
            #pragma unroll
            for (int ni = 0; ni < 2; ++ni)
                d[mi][ni] = __builtin_amdgcn_mfma_f32_16x16x32_f16(
                    a[mi], b[ni], (f32x4)(0.f), 0, 0, 0);

        if (pi == 0) {   // P0: row-major left operand for L2
            const int base = PL_H + ba * 1024;
            #pragma unroll
            for (int mi = 0; mi < 2; ++mi)
                #pragma unroll
                for (int ni = 0; ni < 2; ++ni)
                    #pragma unroll
                    for (int q = 0; q < 4; ++q) {
                        const int row = mi * 16 + fq * 4 + q;
                        const int col = ni * 16 + fr;
                        lh[base + row * 32 + (((col >> 3) ^ (row & 3)) << 3) + (col & 7)] =
                            (_Float16)d[mi][ni][q];
                    }
        } else {         // P1: transposed right operand for L2
            const int base = PRT_H + ba * 1024;
            #pragma unroll
            for (int mi = 0; mi < 2; ++mi)
                #pragma unroll
                for (int ni = 0; ni < 2; ++ni)
                    #pragma unroll
                    for (int q = 0; q < 4; ++q) {
                        const int row = mi * 16 + fq * 4 + q;
                        const int col = ni * 16 + fr;
                        lh[base + col * 32 + (((row >> 3) ^ (col & 3)) << 3) + (row & 7)] =
                            (_Float16)d[mi][ni][q];
                    }
        }
    }
    __syncthreads();

    // ---- L2: R = P0 * P1; wave w -> batch (w>>1), row-block (w&1) ----
    {
        const int ba = wid >> 1, mi = wid & 1;
        const int Ab = PL_H  + ba * 1024;
        const int Bb = PRT_H + ba * 1024;
        const half8 a = *(const half8*)&lh[Ab + (mi * 16 + fr) * 32 + ((fq ^ (fr & 3)) << 3)];
        #pragma unroll
        for (int ni = 0; ni < 2; ++ni) {
            const half8 b = *(const half8*)&lh[Bb + (ni * 16 + fr) * 32 + ((fq ^ (fr & 3)) << 3)];
            const f32x4 d = __builtin_amdgcn_mfma_f32_16x16x32_f16(
                a, b, (f32x4)(0.f), 0, 0, 0);
            #pragma unroll
            for (int q = 0; q < 4; ++q) {
                const int row = mi * 16 + fq * 4 + q;
                const int col = ni * 16 + fr;
                smem[ba * 1024 + row * 32 + (((col >> 2) ^ (row & 7)) << 2) + (col & 3)] = d[q];
            }
        }
    }
    __syncthreads();

    // ---- coalesced copy-out (reads back through the f32 swizzle) ----
    #pragma unroll
    for (int s = 0; s < 2; ++s) {
        const int idx = s * 256 + tid;       // 0..511 float4s
        const int ba  = idx >> 8;
        const int f4i = idx & 255;
        const int row = f4i >> 3;
        const int cc  = f4i & 7;
        const f32x4 val = *(const f32x4*)&smem[ba * 1024 + row * 32 + ((cc ^ (row & 7)) << 2)];
        *(f32x4*)(out + (b0 + ba) * 1024 + (size_t)f4i * 4) = val;
    }
}

// ---------------------------------------------------------------------------
extern "C" void kernel_launch(void* const* d_in, const int* in_sizes, int n_in,
                              void* d_out, int out_size, void* d_ws, size_t ws_size,
                              hipStream_t stream)
{
    const float* x  = (const float*)d_in[0];   // [16384, 512]
    const float* W1 = (const float*)d_in[1];   // [1024, 512]
    const float* b1 = (const float*)d_in[2];   // [1024]
    const float* W2 = (const float*)d_in[3];   // [496, 1024]
    const float* b2 = (const float*)d_in[4];   // [496]
    float* out = (float*)d_out;                // [16384, 32, 32]

    float* h  = out;              // d_out (64 MB) doubles as h scratch
    float* cs = (float*)d_ws;     // [16384][496] float2 = 65 MB

    gemm_nt_mfma<0, true><<<dim3(HIDDEN / 128, BATCH / 128), 256, 0, stream>>>(
        x, W1, b1, h, BATCH, HIDDEN, INPUT_DIM, HIDDEN);

    gemm_nt_mfma<1, false><<<dim3((NANG + 127) / 128, BATCH / 128), 256, 0, stream>>>(
        h, W2, b2, cs, BATCH, NANG, HIDDEN, NANG);

    rotate_kernel<<<dim3(BATCH / 2), 256, 0, stream>>>(
        (const float4*)cs, out);
}

// Round 13
// 124.018 us; speedup vs baseline: 2.5548x; 1.1873x over previous
//
#include <hip/hip_runtime.h>
#include <math.h>
#include <utility>

#define BATCH 16384
#define INPUT_DIM 512
#define HIDDEN 1024
#define NROT 32
#define NANG 496   // 32*31/2

typedef _Float16 half8 __attribute__((ext_vector_type(8)));
typedef float    f32x4 __attribute__((ext_vector_type(4)));

// ---------------------------------------------------------------------------
// f32 -> f16 conversion (prep pass), 8 elems/thread
// ---------------------------------------------------------------------------
__global__ __launch_bounds__(256) void cvt_f32_f16(
    const float* __restrict__ src, _Float16* __restrict__ dst, int n8)
{
    const int i = blockIdx.x * 256 + threadIdx.x;
    if (i < n8) {
        const float4* s = (const float4*)src + (size_t)i * 2;
        const float4 a = s[0], b = s[1];
        half8 h;
        h[0]=(_Float16)a.x; h[1]=(_Float16)a.y; h[2]=(_Float16)a.z; h[3]=(_Float16)a.w;
        h[4]=(_Float16)b.x; h[5]=(_Float16)b.y; h[6]=(_Float16)b.z; h[7]=(_Float16)b.w;
        *(half8*)(dst + (size_t)i * 8) = h;
    }
}

// ---------------------------------------------------------------------------
// Single-pass f16 MFMA GEMM (NT): C = epi(A[M,K] @ B[N,K]^T + bias)
// A, B already f16 in HBM -> staging is pure half8 copies (no cvt VALU).
// Tile 128x128xBK32, 4 waves (2x2), LDS 32KB double-buffered, XOR swizzle.
//   EPI=0: relu -> f16 Ch[M][Nout]   (feeds GEMM2's A)
//   EPI=1: sincos -> float2 Cf[M][Nout], col guarded
// ---------------------------------------------------------------------------
template<int EPI>
__global__ __launch_bounds__(256) void gemm_nt_f16(
    const _Float16* __restrict__ A, const _Float16* __restrict__ B,
    const float* __restrict__ bias, float* __restrict__ Cf,
    _Float16* __restrict__ Ch, int M, int N, int K, int Nout)
{
    constexpr int BK = 32;                    // K per stage (f16 elems)
    __shared__ _Float16 sA[2][128 * BK];      // 8 KB each
    __shared__ _Float16 sB[2][128 * BK];      // total 32 KB

    const int tid = threadIdx.x;
    const int m0 = blockIdx.y * 128;
    const int n0 = blockIdx.x * 128;

    const int rA  = tid >> 2;                       // 0..63
    const int k8  = tid & 3;
    const int swW = ((k8 ^ (rA & 3)) << 3);         // swizzled f16 offset in row

    half8 rg[4];

    auto load_tile = [&](int kt) {
        const size_t koff = (size_t)kt * BK + k8 * 8;
        rg[0] = *(const half8*)(A + (size_t)(m0 + rA) * K + koff);
        rg[1] = *(const half8*)(A + (size_t)(m0 + rA + 64) * K + koff);
        half8 z;
        #pragma unroll
        for (int j = 0; j < 8; ++j) z[j] = (_Float16)0.f;
        if (EPI == 0 || (n0 + rA) < N)
            rg[2] = *(const half8*)(B + (size_t)(n0 + rA) * K + koff);
        else rg[2] = z;
        if (EPI == 0 || (n0 + rA + 64) < N)
            rg[3] = *(const half8*)(B + (size_t)(n0 + rA + 64) * K + koff);
        else rg[3] = z;
    };

    auto write_tile = [&](int buf) {
        *(half8*)&sA[buf][ rA       * BK + swW] = rg[0];
        *(half8*)&sA[buf][(rA + 64) * BK + swW] = rg[1];
        *(half8*)&sB[buf][ rA       * BK + swW] = rg[2];
        *(half8*)&sB[buf][(rA + 64) * BK + swW] = rg[3];
    };

    const int lane = tid & 63;
    const int wid  = tid >> 6;
    const int wr = wid >> 1, wc = wid & 1;
    const int fr = lane & 15, fq = lane >> 4;
    const int swR   = ((fq ^ (fr & 3)) << 3);
    const int aBase = (wr * 64 + fr) * BK + swR;
    const int bBase = (wc * 64 + fr) * BK + swR;

    f32x4 acc[4][4];
    #pragma unroll
    for (int i = 0; i < 4; ++i)
        #pragma unroll
        for (int j = 0; j < 4; ++j) acc[i][j] = (f32x4)(0.f);

    const int NT = K / BK;
    load_tile(0);
    write_tile(0);
    int cur = 0;

    for (int kt = 0; kt < NT; ++kt) {
        const bool more = (kt + 1 < NT);
        if (more) load_tile(kt + 1);        // in flight across barrier + MFMA
        __syncthreads();

        half8 a_[4], b_[4];
        #pragma unroll
        for (int f = 0; f < 4; ++f) {
            a_[f] = *(const half8*)&sA[cur][aBase + f * 16 * BK];
            b_[f] = *(const half8*)&sB[cur][bBase + f * 16 * BK];
        }
        #pragma unroll
        for (int fm = 0; fm < 4; ++fm)
            #pragma unroll
            for (int fn = 0; fn < 4; ++fn)
                acc[fm][fn] = __builtin_amdgcn_mfma_f32_16x16x32_f16(
                    a_[fm], b_[fn], acc[fm][fn], 0, 0, 0);

        if (more) write_tile(cur ^ 1);      // buf^1's readers finished at barrier
        cur ^= 1;
    }

    if (EPI == 0) {
        #pragma unroll
        for (int fn = 0; fn < 4; ++fn) {
            const int col = n0 + wc * 64 + fn * 16 + fr;
            const float bv = bias[col];
            #pragma unroll
            for (int fm = 0; fm < 4; ++fm) {
                const int row0 = m0 + wr * 64 + fm * 16 + fq * 4;
                #pragma unroll
                for (int r = 0; r < 4; ++r)
                    Ch[(size_t)(row0 + r) * Nout + col] =
                        (_Float16)fmaxf(acc[fm][fn][r] + bv, 0.f);
            }
        }
    } else {
        #pragma unroll
        for (int fn = 0; fn < 4; ++fn) {
            const int col = n0 + wc * 64 + fn * 16 + fr;
            if (col < Nout) {
                const float bv = bias[col];
                #pragma unroll
                for (int fm = 0; fm < 4; ++fm) {
                    const int row0 = m0 + wr * 64 + fm * 16 + fq * 4;
                    #pragma unroll
                    for (int r = 0; r < 4; ++r) {
                        const float ang = acc[fm][fn][r] + bv;
                        float s, c;
                        __sincosf(ang, &s, &c);
                        *(float2*)(Cf + ((size_t)(row0 + r) * Nout + col) * 2) =
                            make_float2(c, s);
                    }
                }
            }
        }
    }
}

// ---------------------------------------------------------------------------
// Rotate — chunked chain + MFMA combine tree (unchanged from round 12).
// ---------------------------------------------------------------------------
struct IJTbl { unsigned char i[NANG]; unsigned char j[NANG]; };
constexpr IJTbl make_ij_tbl() {
    IJTbl t{};
    int k = 0;
    for (int i = 0; i < NROT - 1; ++i)
        for (int j = i + 1; j < NROT; ++j) { t.i[k] = (unsigned char)i; t.j[k] = (unsigned char)j; ++k; }
    return t;
}
constexpr IJTbl IJT = make_ij_tbl();

template<int M>   // M = f4 index 0..247: rotations 2M, 2M+1
__device__ __forceinline__ void rot_pair(const f32x4 q, float (&v)[NROT]) {
    {
        constexpr int k = 2 * M;
        constexpr int i = IJT.i[k], j = IJT.j[k];
        const float vi = v[i], vj = v[j];
        v[i] = fmaf(q[0], vi,  q[1] * vj);
        v[j] = fmaf(q[0], vj, -q[1] * vi);
    }
    {
        constexpr int k = 2 * M + 1;
        constexpr int i = IJT.i[k], j = IJT.j[k];
        const float vi = v[i], vj = v[j];
        v[i] = fmaf(q[2], vi,  q[3] * vj);
        v[j] = fmaf(q[2], vj, -q[3] * vi);
    }
}

template<int W, int T>
__device__ __forceinline__ void chain_grp(const float* __restrict__ lcs,
                                          float (&v)[NROT]) {
    const f32x4 q = *(const f32x4*)(lcs + (62 * W + T) * 4);
    rot_pair<62 * W + T>(q, v);
}

template<int W, size_t... Ts>
__device__ __forceinline__ void chain_runW(const float* __restrict__ lcs,
                                           float (&v)[NROT],
                                           std::index_sequence<Ts...>) {
    (chain_grp<W, (int)Ts>(lcs, v), ...);
}

// f16 LDS region bases (f16 index units)
#define LROW_H 4096
#define RT_H   8192
#define PL_H   12288
#define PRT_H  14336

template<int W>
__device__ __forceinline__ void chain_and_store(const float* __restrict__ lcs,
                                                _Float16* __restrict__ lh,
                                                int half, int r) {
    float v[NROT];
    #pragma unroll
    for (int c = 0; c < NROT; ++c) v[c] = (c == r) ? 1.f : 0.f;
    chain_runW<W>(lcs, v, std::make_index_sequence<62>{});

    if constexpr ((W & 1) == 0) {
        const int base = LROW_H + (half * 2 + (W >> 1)) * 1024;
        #pragma unroll
        for (int kq = 0; kq < 4; ++kq) {
            half8 hv;
            #pragma unroll
            for (int j = 0; j < 8; ++j) hv[j] = (_Float16)v[kq * 8 + j];
            *(half8*)&lh[base + r * 32 + ((kq ^ (r & 3)) << 3)] = hv;
        }
    } else {
        const int base = RT_H + (half * 2 + (W >> 1)) * 1024;
        #pragma unroll
        for (int c = 0; c < NROT; ++c)
            lh[base + c * 32 + (((r >> 3) ^ (c & 3)) << 3) + (r & 7)] =
                (_Float16)v[c];
    }
}

__global__ __launch_bounds__(256) void rotate_kernel(
    const float4* __restrict__ cs4, float* __restrict__ out)
{
    __shared__ float smem[8192];   // 32 KB
    _Float16* lh = (_Float16*)smem;

    const int tid  = threadIdx.x;
    const int wid  = tid >> 6;
    const int lane = tid & 63;
    const int half = (tid >> 5) & 1;
    const int r    = tid & 31;
    const int fr = lane & 15, fq = lane >> 4;
    const size_t b0 = (size_t)blockIdx.x * 2;

    float4* l4 = (float4*)smem;
    #pragma unroll
    for (int t = 0; t < 2; ++t) {
        const int idx = t * 256 + tid;
        if (idx < 496) {
            const int ba = idx >= 248;
            const int m  = idx - ba * 248;
            l4[ba * 248 + m] = cs4[(b0 + ba) * 248 + m];
        }
    }
    __syncthreads();

    const float* lcs = smem + half * 992;
    if      (wid == 0) chain_and_store<0>(lcs, lh, half, r);
    else if (wid == 1) chain_and_store<1>(lcs, lh, half, r);
    else if (wid == 2) chain_and_store<2>(lcs, lh, half, r);
    else               chain_and_store<3>(lcs, lh, half, r);
    __syncthreads();

    {
        const int ba = wid >> 1, pi = wid & 1;
        const int Ab = LROW_H + (ba * 2 + pi) * 1024;
        const int Bb = RT_H   + (ba * 2 + pi) * 1024;
        half8 a[2], b[2];
        #pragma unroll
        for (int mi = 0; mi < 2; ++mi) {
            a[mi] = *(const half8*)&lh[Ab + (mi * 16 + fr) * 32 + ((fq ^ (fr & 3)) << 3)];
            b[mi] = *(const half8*)&lh[Bb + (mi * 16 + fr) * 32 + ((fq ^ (fr & 3)) << 3)];
        }
        f32x4 d[2][2];
        #pragma unroll
        for (int mi = 0; mi < 2; ++mi)
            #pragma unroll
            for (int ni = 0; ni < 2; ++ni)
                d[mi][ni] = __builtin_amdgcn_mfma_f32_16x16x32_f16(
                    a[mi], b[ni], (f32x4)(0.f), 0, 0, 0);

        if (pi == 0) {
            const int base = PL_H + ba * 1024;
            #pragma unroll
            for (int mi = 0; mi < 2; ++mi)
                #pragma unroll
                for (int ni = 0; ni < 2; ++ni)
                    #pragma unroll
                    for (int q = 0; q < 4; ++q) {
                        const int row = mi * 16 + fq * 4 + q;
                        const int col = ni * 16 + fr;
                        lh[base + row * 32 + (((col >> 3) ^ (row & 3)) << 3) + (col & 7)] =
                            (_Float16)d[mi][ni][q];
                    }
        } else {
            const int base = PRT_H + ba * 1024;
            #pragma unroll
            for (int mi = 0; mi < 2; ++mi)
                #pragma unroll
                for (int ni = 0; ni < 2; ++ni)
                    #pragma unroll
                    for (int q = 0; q < 4; ++q) {
                        const int row = mi * 16 + fq * 4 + q;
                        const int col = ni * 16 + fr;
                        lh[base + col * 32 + (((row >> 3) ^ (col & 3)) << 3) + (row & 7)] =
                            (_Float16)d[mi][ni][q];
                    }
        }
    }
    __syncthreads();

    {
        const int ba = wid >> 1, mi = wid & 1;
        const int Ab = PL_H  + ba * 1024;
        const int Bb = PRT_H + ba * 1024;
        const half8 a = *(const half8*)&lh[Ab + (mi * 16 + fr) * 32 + ((fq ^ (fr & 3)) << 3)];
        #pragma unroll
        for (int ni = 0; ni < 2; ++ni) {
            const half8 b = *(const half8*)&lh[Bb + (ni * 16 + fr) * 32 + ((fq ^ (fr & 3)) << 3)];
            const f32x4 d = __builtin_amdgcn_mfma_f32_16x16x32_f16(
                a, b, (f32x4)(0.f), 0, 0, 0);
            #pragma unroll
            for (int q = 0; q < 4; ++q) {
                const int row = mi * 16 + fq * 4 + q;
                const int col = ni * 16 + fr;
                smem[ba * 1024 + row * 32 + (((col >> 2) ^ (row & 7)) << 2) + (col & 3)] = d[q];
            }
        }
    }
    __syncthreads();

    #pragma unroll
    for (int s = 0; s < 2; ++s) {
        const int idx = s * 256 + tid;
        const int ba  = idx >> 8;
        const int f4i = idx & 255;
        const int row = f4i >> 3;
        const int cc  = f4i & 7;
        const f32x4 val = *(const f32x4*)&smem[ba * 1024 + row * 32 + ((cc ^ (row & 7)) << 2)];
        *(f32x4*)(out + (b0 + ba) * 1024 + (size_t)f4i * 4) = val;
    }
}

// ---------------------------------------------------------------------------
extern "C" void kernel_launch(void* const* d_in, const int* in_sizes, int n_in,
                              void* d_out, int out_size, void* d_ws, size_t ws_size,
                              hipStream_t stream)
{
    const float* x  = (const float*)d_in[0];   // [16384, 512]
    const float* W1 = (const float*)d_in[1];   // [1024, 512]
    const float* b1 = (const float*)d_in[2];   // [1024]
    const float* W2 = (const float*)d_in[3];   // [496, 1024]
    const float* b2 = (const float*)d_in[4];   // [496]
    float* out = (float*)d_out;                // [16384, 32, 32]

    // d_out (67.1 MB) doubles as f16 scratch; rotate rewrites all of it last.
    _Float16* h16  = (_Float16*)d_out;               // 33.55 MB
    _Float16* x16  = h16  + (size_t)BATCH * HIDDEN;  // 16.78 MB
    _Float16* W116 = x16  + (size_t)BATCH * INPUT_DIM;
    _Float16* W216 = W116 + (size_t)HIDDEN * INPUT_DIM;
    float*    cs   = (float*)d_ws;                   // [16384][496] float2

    // prep: f32 -> f16 (x, W1, W2)
    cvt_f32_f16<<<dim3((BATCH * INPUT_DIM / 8 + 255) / 256), 256, 0, stream>>>(
        x, x16, BATCH * INPUT_DIM / 8);
    cvt_f32_f16<<<dim3((HIDDEN * INPUT_DIM / 8 + 255) / 256), 256, 0, stream>>>(
        W1, W116, HIDDEN * INPUT_DIM / 8);
    cvt_f32_f16<<<dim3((NANG * HIDDEN / 8 + 255) / 256), 256, 0, stream>>>(
        W2, W216, NANG * HIDDEN / 8);

    // h16 = f16(relu(x @ W1^T + b1))
    gemm_nt_f16<0><<<dim3(HIDDEN / 128, BATCH / 128), 256, 0, stream>>>(
        x16, W116, b1, nullptr, h16, BATCH, HIDDEN, INPUT_DIM, HIDDEN);

    // cs = (cos,sin)(h16 @ W2^T + b2)
    gemm_nt_f16<1><<<dim3((NANG + 127) / 128, BATCH / 128), 256, 0, stream>>>(
        h16, W216, b2, cs, nullptr, BATCH, NANG, HIDDEN, NANG);

    // R = Givens chain via chunked chains + MFMA tree
    rotate_kernel<<<dim3(BATCH / 2), 256, 0, stream>>>(
        (const float4*)cs, out);
}

// Round 15
// 119.484 us; speedup vs baseline: 2.6518x; 1.0379x over previous
//
#include <hip/hip_runtime.h>
#include <math.h>
#include <utility>

#define BATCH 16384
#define INPUT_DIM 512
#define HIDDEN 1024
#define NROT 32
#define NANG 496   // 32*31/2

typedef _Float16 half8 __attribute__((ext_vector_type(8)));
typedef _Float16 half4 __attribute__((ext_vector_type(4)));
typedef float    f32x4 __attribute__((ext_vector_type(4)));

// ---------------------------------------------------------------------------
// f32 -> f16 conversion (prep pass), 8 elems/thread
// ---------------------------------------------------------------------------
__global__ __launch_bounds__(256) void cvt_f32_f16(
    const float* __restrict__ src, _Float16* __restrict__ dst, int n8)
{
    const int i = blockIdx.x * 256 + threadIdx.x;
    if (i < n8) {
        const float4* s = (const float4*)src + (size_t)i * 2;
        const float4 a = s[0], b = s[1];
        half8 h;
        h[0]=(_Float16)a.x; h[1]=(_Float16)a.y; h[2]=(_Float16)a.z; h[3]=(_Float16)a.w;
        h[4]=(_Float16)b.x; h[5]=(_Float16)b.y; h[6]=(_Float16)b.z; h[7]=(_Float16)b.w;
        *(half8*)(dst + (size_t)i * 8) = h;
    }
}

// ---------------------------------------------------------------------------
// Single-pass f16 MFMA GEMM (NT): C = epi(A[M,K] @ B[N,K]^T + bias)
//   EPI=0: relu -> f16 Ch[M][Nout]
//   EPI=1: theta -> f32 Cf[M][Nout] (raw angle; sincos moved to rotate)
// ---------------------------------------------------------------------------
template<int EPI>
__global__ __launch_bounds__(256) void gemm_nt_f16(
    const _Float16* __restrict__ A, const _Float16* __restrict__ B,
    const float* __restrict__ bias, float* __restrict__ Cf,
    _Float16* __restrict__ Ch, int M, int N, int K, int Nout)
{
    constexpr int BK = 32;
    __shared__ _Float16 sA[2][128 * BK];
    __shared__ _Float16 sB[2][128 * BK];

    const int tid = threadIdx.x;
    const int m0 = blockIdx.y * 128;
    const int n0 = blockIdx.x * 128;

    const int rA  = tid >> 2;
    const int k8  = tid & 3;
    const int swW = ((k8 ^ (rA & 3)) << 3);

    half8 rg[4];

    auto load_tile = [&](int kt) {
        const size_t koff = (size_t)kt * BK + k8 * 8;
        rg[0] = *(const half8*)(A + (size_t)(m0 + rA) * K + koff);
        rg[1] = *(const half8*)(A + (size_t)(m0 + rA + 64) * K + koff);
        half8 z;
        #pragma unroll
        for (int j = 0; j < 8; ++j) z[j] = (_Float16)0.f;
        if (EPI == 0 || (n0 + rA) < N)
            rg[2] = *(const half8*)(B + (size_t)(n0 + rA) * K + koff);
        else rg[2] = z;
        if (EPI == 0 || (n0 + rA + 64) < N)
            rg[3] = *(const half8*)(B + (size_t)(n0 + rA + 64) * K + koff);
        else rg[3] = z;
    };

    auto write_tile = [&](int buf) {
        *(half8*)&sA[buf][ rA       * BK + swW] = rg[0];
        *(half8*)&sA[buf][(rA + 64) * BK + swW] = rg[1];
        *(half8*)&sB[buf][ rA       * BK + swW] = rg[2];
        *(half8*)&sB[buf][(rA + 64) * BK + swW] = rg[3];
    };

    const int lane = tid & 63;
    const int wid  = tid >> 6;
    const int wr = wid >> 1, wc = wid & 1;
    const int fr = lane & 15, fq = lane >> 4;
    const int swR   = ((fq ^ (fr & 3)) << 3);
    const int aBase = (wr * 64 + fr) * BK + swR;
    const int bBase = (wc * 64 + fr) * BK + swR;

    f32x4 acc[4][4];
    #pragma unroll
    for (int i = 0; i < 4; ++i)
        #pragma unroll
        for (int j = 0; j < 4; ++j) acc[i][j] = (f32x4)(0.f);

    const int NT = K / BK;
    load_tile(0);
    write_tile(0);
    int cur = 0;

    for (int kt = 0; kt < NT; ++kt) {
        const bool more = (kt + 1 < NT);
        if (more) load_tile(kt + 1);
        __syncthreads();

        half8 a_[4], b_[4];
        #pragma unroll
        for (int f = 0; f < 4; ++f) {
            a_[f] = *(const half8*)&sA[cur][aBase + f * 16 * BK];
            b_[f] = *(const half8*)&sB[cur][bBase + f * 16 * BK];
        }
        #pragma unroll
        for (int fm = 0; fm < 4; ++fm)
            #pragma unroll
            for (int fn = 0; fn < 4; ++fn)
                acc[fm][fn] = __builtin_amdgcn_mfma_f32_16x16x32_f16(
                    a_[fm], b_[fn], acc[fm][fn], 0, 0, 0);

        if (more) write_tile(cur ^ 1);
        cur ^= 1;
    }

    if (EPI == 0) {
        #pragma unroll
        for (int fn = 0; fn < 4; ++fn) {
            const int col = n0 + wc * 64 + fn * 16 + fr;
            const float bv = bias[col];
            #pragma unroll
            for (int fm = 0; fm < 4; ++fm) {
                const int row0 = m0 + wr * 64 + fm * 16 + fq * 4;
                #pragma unroll
                for (int r = 0; r < 4; ++r)
                    Ch[(size_t)(row0 + r) * Nout + col] =
                        (_Float16)fmaxf(acc[fm][fn][r] + bv, 0.f);
            }
        }
    } else {
        #pragma unroll
        for (int fn = 0; fn < 4; ++fn) {
            const int col = n0 + wc * 64 + fn * 16 + fr;
            if (col < Nout) {
                const float bv = bias[col];
                #pragma unroll
                for (int fm = 0; fm < 4; ++fm) {
                    const int row0 = m0 + wr * 64 + fm * 16 + fq * 4;
                    #pragma unroll
                    for (int r = 0; r < 4; ++r)
                        Cf[(size_t)(row0 + r) * Nout + col] = acc[fm][fn][r] + bv;
                }
            }
        }
    }
}

// ---------------------------------------------------------------------------
// Rotate — chunked chains (row chains even / column chains odd) + MFMA tree.
// NT-mfma semantics: mfma(a,b) = A @ B^T with both operands row-fragments.
//   Chains: EVEN region = C_even rows; ODD region = C_odd^T rows (column
//   chain = reverse-order rotations w/ transposed rule), both vector-stored.
//   L1 (FIXED vs R14):
//     pi=0: D = mfma(C1^T, C0)   = C1^T @ C0^T = P0^T; column-major store
//           -> PCM0 = (P0^T)^T = P0 ROW-major.
//     pi=1: D = mfma(C2,   C3^T) = C2 @ C3     = P1;   column-major store
//           -> PCM1 = P1^T row-major.
//   L2: D = mfma(PCM1, PCM0) = P1^T @ P0^T = R^T; lane's 4 values = 4
//       consecutive COLUMNS of R at fixed row -> vector b128 stores.
//   (R14 bug: both P's stored as P^T made L2 compute P1^T @ P0 != R^T.)
// LDS 24KB via overlays -> 6 blocks/CU.
// ---------------------------------------------------------------------------
struct IJTbl { unsigned char i[NANG]; unsigned char j[NANG]; };
constexpr IJTbl make_ij_tbl() {
    IJTbl t{};
    int k = 0;
    for (int i = 0; i < NROT - 1; ++i)
        for (int j = i + 1; j < NROT; ++j) { t.i[k] = (unsigned char)i; t.j[k] = (unsigned char)j; ++k; }
    return t;
}
constexpr IJTbl IJT = make_ij_tbl();

#define EVEN_H 4096    // f16 index of even-factor region (= f32 2048)
#define ODD_H  8192    // f16 index of odd-factor region  (= f32 4096)
#define PCM_H  0       // f16 index of P region (column-major D stores)
#define RF32   2048    // f32 index of R output region

template<int M>   // forward: rotations 2M then 2M+1 (row rule)
__device__ __forceinline__ void rot_fwd(const f32x4 q, float (&v)[NROT]) {
    {
        constexpr int k = 2 * M;
        constexpr int i = IJT.i[k], j = IJT.j[k];
        const float vi = v[i], vj = v[j];
        v[i] = fmaf(q[0], vi,  q[1] * vj);
        v[j] = fmaf(q[0], vj, -q[1] * vi);
    }
    {
        constexpr int k = 2 * M + 1;
        constexpr int i = IJT.i[k], j = IJT.j[k];
        const float vi = v[i], vj = v[j];
        v[i] = fmaf(q[2], vi,  q[3] * vj);
        v[j] = fmaf(q[2], vj, -q[3] * vi);
    }
}

template<int M>   // reverse: rotations 2M+1 then 2M (column rule)
__device__ __forceinline__ void rot_rev(const f32x4 q, float (&v)[NROT]) {
    {
        constexpr int k = 2 * M + 1;
        constexpr int i = IJT.i[k], j = IJT.j[k];
        const float vi = v[i], vj = v[j];
        v[i] = fmaf(q[2], vi, -q[3] * vj);
        v[j] = fmaf(q[2], vj,  q[3] * vi);
    }
    {
        constexpr int k = 2 * M;
        constexpr int i = IJT.i[k], j = IJT.j[k];
        const float vi = v[i], vj = v[j];
        v[i] = fmaf(q[0], vi, -q[1] * vj);
        v[j] = fmaf(q[0], vj,  q[1] * vi);
    }
}

template<int W, int T>
__device__ __forceinline__ void chain_step(const float* __restrict__ lcs,
                                           float (&v)[NROT]) {
    if constexpr ((W & 1) == 0) {
        constexpr int fi = 62 * W + T;                 // forward order
        const f32x4 q = *(const f32x4*)(lcs + fi * 4);
        rot_fwd<fi>(q, v);
    } else {
        constexpr int fi = 62 * W + (61 - T);          // reverse order
        const f32x4 q = *(const f32x4*)(lcs + fi * 4);
        rot_rev<fi>(q, v);
    }
}

template<int W, size_t... Ts>
__device__ __forceinline__ void chain_runW(const float* __restrict__ lcs,
                                           float (&v)[NROT],
                                           std::index_sequence<Ts...>) {
    (chain_step<W, (int)Ts>(lcs, v), ...);
}

template<int W>
__device__ __forceinline__ void chain_and_store(const float* __restrict__ lcs,
                                                _Float16* __restrict__ lh,
                                                int half, int r) {
    float v[NROT];
    #pragma unroll
    for (int c = 0; c < NROT; ++c) v[c] = (c == r) ? 1.f : 0.f;
    chain_runW<W>(lcs, v, std::make_index_sequence<62>{});

    // even: row r of C; odd: row r of C^T — identical vectorized store.
    constexpr int REG = ((W & 1) == 0) ? EVEN_H : ODD_H;
    const int base = REG + (half * 2 + (W >> 1)) * 1024;
    #pragma unroll
    for (int kq = 0; kq < 4; ++kq) {
        half8 hv;
        #pragma unroll
        for (int j = 0; j < 8; ++j) hv[j] = (_Float16)v[kq * 8 + j];
        *(half8*)&lh[base + r * 32 + ((kq ^ (r & 3)) << 3)] = hv;
    }
}

__global__ __launch_bounds__(256) void rotate_kernel(
    const float* __restrict__ theta, float* __restrict__ out)
{
    __shared__ float smem[6144];   // 24 KB
    _Float16* lh = (_Float16*)smem;

    const int tid  = threadIdx.x;
    const int wid  = tid >> 6;
    const int lane = tid & 63;
    const int half = (tid >> 5) & 1;       // batch within block (chain phase)
    const int r    = tid & 31;             // row / column index
    const int fr = lane & 15, fq = lane >> 4;
    const size_t b0 = (size_t)blockIdx.x * 2;

    // ---- stage: load theta, sincos once, write (c,s) pairs ----
    if (tid < 248) {
        const f32x4 th = *(const f32x4*)(theta + b0 * NANG + tid * 4);
        f32x4 p0, p1;
        float s, c;
        __sincosf(th[0], &s, &c); p0[0] = c; p0[1] = s;
        __sincosf(th[1], &s, &c); p0[2] = c; p0[3] = s;
        __sincosf(th[2], &s, &c); p1[0] = c; p1[1] = s;
        __sincosf(th[3], &s, &c); p1[2] = c; p1[3] = s;
        *(f32x4*)&smem[tid * 8]     = p0;
        *(f32x4*)&smem[tid * 8 + 4] = p1;
    }
    __syncthreads();

    // ---- chunk chains (wave-uniform branch) ----
    const float* lcs = smem + half * 992;
    if      (wid == 0) chain_and_store<0>(lcs, lh, half, r);
    else if (wid == 1) chain_and_store<1>(lcs, lh, half, r);
    else if (wid == 2) chain_and_store<2>(lcs, lh, half, r);
    else               chain_and_store<3>(lcs, lh, half, r);
    __syncthreads();

    // ---- L1: wave (ba,pi) ----
    //  pi=0: D = mfma(C1^T, C0)  = P0^T  -> col-major store => PCM0 = P0 rows
    //  pi=1: D = mfma(C2, C3^T)  = P1    -> col-major store => PCM1 = P1^T rows
    {
        const int ba = wid >> 1, pi = wid & 1;
        const int Eb = EVEN_H + (ba * 2 + pi) * 1024;   // C_{2pi} rows
        const int Ob = ODD_H  + (ba * 2 + pi) * 1024;   // C_{2pi+1}^T rows
        const int Asrc = (pi == 0) ? Ob : Eb;
        const int Bsrc = (pi == 0) ? Eb : Ob;
        const int swz = (fq ^ (fr & 3)) << 3;
        half8 a[2], b[2];
        #pragma unroll
        for (int mi = 0; mi < 2; ++mi) {
            a[mi] = *(const half8*)&lh[Asrc + (mi * 16 + fr) * 32 + swz];
            b[mi] = *(const half8*)&lh[Bsrc + (mi * 16 + fr) * 32 + swz];
        }
        const int Pb = PCM_H + (ba * 2 + pi) * 1024;
        #pragma unroll
        for (int mi = 0; mi < 2; ++mi)
            #pragma unroll
            for (int ni = 0; ni < 2; ++ni) {
                const f32x4 d = __builtin_amdgcn_mfma_f32_16x16x32_f16(
                    a[mi], b[ni], (f32x4)(0.f), 0, 0, 0);
                half4 hv;
                #pragma unroll
                for (int q = 0; q < 4; ++q) hv[q] = (_Float16)d[q];
                const int col  = ni * 16 + fr;
                const int rowb = (mi * 16 + fq * 4) ^ ((col & 3) << 3);
                *(half4*)&lh[Pb + col * 32 + rowb] = hv;
            }
    }
    __syncthreads();

    // ---- L2: D = mfma(PCM1, PCM0) = P1^T @ P0^T = R^T; lane holds 4
    //      consecutive COLUMNS of R at fixed row -> b128 stores.
    {
        const int ba = wid >> 1, mi = wid & 1;
        const int Ab = PCM_H + (ba * 2 + 1) * 1024;   // P1^T rows
        const int Bb = PCM_H + (ba * 2 + 0) * 1024;   // P0 rows
        const int swz = (fq ^ (fr & 3)) << 3;
        const half8 a = *(const half8*)&lh[Ab + (mi * 16 + fr) * 32 + swz];
        #pragma unroll
        for (int ni = 0; ni < 2; ++ni) {
            const half8 b = *(const half8*)&lh[Bb + (ni * 16 + fr) * 32 + swz];
            const f32x4 d = __builtin_amdgcn_mfma_f32_16x16x32_f16(
                a, b, (f32x4)(0.f), 0, 0, 0);
            const int row  = ni * 16 + fr;            // row of R
            const int colq = mi * 4 + fq;             // col block (4 f32)
            *(f32x4*)&smem[RF32 + ba * 1024 + row * 32 + ((colq ^ (row & 7)) << 2)] = d;
        }
    }
    __syncthreads();

    // ---- coalesced copy-out ----
    #pragma unroll
    for (int s = 0; s < 2; ++s) {
        const int idx = s * 256 + tid;
        const int ba  = idx >> 8;
        const int f4i = idx & 255;
        const int row = f4i >> 3;
        const int cc  = f4i & 7;
        const f32x4 val =
            *(const f32x4*)&smem[RF32 + ba * 1024 + row * 32 + ((cc ^ (row & 7)) << 2)];
        *(f32x4*)(out + (b0 + ba) * 1024 + (size_t)f4i * 4) = val;
    }
}

// ---------------------------------------------------------------------------
extern "C" void kernel_launch(void* const* d_in, const int* in_sizes, int n_in,
                              void* d_out, int out_size, void* d_ws, size_t ws_size,
                              hipStream_t stream)
{
    const float* x  = (const float*)d_in[0];   // [16384, 512]
    const float* W1 = (const float*)d_in[1];   // [1024, 512]
    const float* b1 = (const float*)d_in[2];   // [1024]
    const float* W2 = (const float*)d_in[3];   // [496, 1024]
    const float* b2 = (const float*)d_in[4];   // [496]
    float* out = (float*)d_out;                // [16384, 32, 32]

    // d_out (67.1 MB) doubles as f16 scratch; rotate rewrites all of it last.
    _Float16* h16  = (_Float16*)d_out;               // 33.55 MB
    _Float16* x16  = h16  + (size_t)BATCH * HIDDEN;  // 16.78 MB
    _Float16* W116 = x16  + (size_t)BATCH * INPUT_DIM;
    _Float16* W216 = W116 + (size_t)HIDDEN * INPUT_DIM;
    float*    th   = (float*)d_ws;                   // theta [16384][496] f32

    cvt_f32_f16<<<dim3((BATCH * INPUT_DIM / 8 + 255) / 256), 256, 0, stream>>>(
        x, x16, BATCH * INPUT_DIM / 8);
    cvt_f32_f16<<<dim3((HIDDEN * INPUT_DIM / 8 + 255) / 256), 256, 0, stream>>>(
        W1, W116, HIDDEN * INPUT_DIM / 8);
    cvt_f32_f16<<<dim3((NANG * HIDDEN / 8 + 255) / 256), 256, 0, stream>>>(
        W2, W216, NANG * HIDDEN / 8);

    gemm_nt_f16<0><<<dim3(HIDDEN / 128, BATCH / 128), 256, 0, stream>>>(
        x16, W116, b1, nullptr, h16, BATCH, HIDDEN, INPUT_DIM, HIDDEN);

    gemm_nt_f16<1><<<dim3((NANG + 127) / 128, BATCH / 128), 256, 0, stream>>>(
        h16, W216, b2, th, nullptr, BATCH, NANG, HIDDEN, NANG);

    rotate_kernel<<<dim3(BATCH / 2), 256, 0, stream>>>(th, out);
}